// Round 4
// baseline (2273.800 us; speedup 1.0000x reference)
//
#include <hip/hip_runtime.h>
#include <math.h>

// ---------------------------------------------------------------------------
// MeshNodeUpdate: edge segment-sum -> concat -> MLP(512->512->256->256, SiLU)
// -> global LayerNorm (stats over ALL elements) -> mx + h, plus pass-throughs.
// MLP runs on matrix cores in bf16 (mfma_f32_16x16x32_bf16); LN in fp32/f64.
// Index tensors are VALUE-converted int32 -> float32 (harness reads d_out as
// float32 for every output).
// ---------------------------------------------------------------------------

constexpr int kMNUM  = 40962;
constexpr int kEDGES = 327680;
constexpr int kGX    = 65536;

// ---- output layout (flat element offsets, all 4-byte elements) ----
constexpr size_t N_GX  = (size_t)kGX * 256;
constexpr size_t N_MX  = (size_t)kMNUM * 256;
constexpr size_t N_MEI = 2ull * kEDGES;
constexpr size_t N_MEX = (size_t)kEDGES * 256;
constexpr size_t N_G2I = 200000;
constexpr size_t N_G2X = 100000ull * 256;
constexpr size_t N_M2I = 200000;
constexpr size_t N_M2X = 100000ull * 256;

constexpr size_t O_GX  = 0;
constexpr size_t O_MX  = O_GX + N_GX;
constexpr size_t O_MEI = O_MX + N_MX;
constexpr size_t O_MEX = O_MEI + N_MEI;
constexpr size_t O_G2I = O_MEX + N_MEX;
constexpr size_t O_G2X = O_G2I + N_G2I;
constexpr size_t O_M2I = O_G2X + N_G2X;
constexpr size_t O_M2X = O_M2I + N_M2I;

// ---- workspace layout (BYTE offsets). Totals ~190 MB. ----
constexpr size_t B_H0  = 0;                                   // f32 [40962][512]
constexpr size_t B_H0B = B_H0  + (size_t)kMNUM * 512 * 4;     // bf16 [40962][512]
constexpr size_t B_H1B = B_H0B + (size_t)kMNUM * 512 * 2;     // bf16 [40962][512]
constexpr size_t B_H3  = B_H1B;                               // f32 [40962][256] (alias; h1b dead, exact byte fit)
constexpr size_t B_H2B = B_H1B + (size_t)kMNUM * 512 * 2;     // bf16 [40962][256]
constexpr size_t B_WB  = B_H2B + (size_t)kMNUM * 256 * 2;     // bf16 weights
constexpr size_t B_SUM = B_WB  + 458752ull * 2;               // 2 doubles
// Wb sub-offsets (elements)
constexpr size_t WB_W1 = 0;
constexpr size_t WB_W2 = 512ull * 512;
constexpr size_t WB_W3 = WB_W2 + 256ull * 512;

typedef __attribute__((ext_vector_type(8))) short bf16x8;
typedef __attribute__((ext_vector_type(4))) float f32x4;

__device__ __forceinline__ unsigned short f2b(float f) {   // fp32->bf16 RNE
    unsigned int u = __float_as_uint(f);
    return (unsigned short)((u + 0x7fffu + ((u >> 16) & 1u)) >> 16);
}

__device__ __forceinline__ void gload_lds16(const void* gsrc, void* ldst) {
    __builtin_amdgcn_global_load_lds(
        (const __attribute__((address_space(1))) unsigned int*)gsrc,
        (__attribute__((address_space(3))) unsigned int*)ldst, 16, 0, 0);
}

// ---------------------------------------------------------------------------
__global__ __launch_bounds__(256) void i2f_kernel(
    const int* __restrict__ in, float* __restrict__ out, int n4)
{
    int idx = blockIdx.x * 256 + threadIdx.x;
    if (idx >= n4) return;
    int4 v = ((const int4*)in)[idx];
    ((float4*)out)[idx] = make_float4((float)v.x, (float)v.y, (float)v.z, (float)v.w);
}

// fp32 -> bf16 (n multiple of 4; one float4 -> one short4 per thread)
__global__ __launch_bounds__(256) void f2b_kernel(
    const float* __restrict__ in, unsigned short* __restrict__ out, int n4)
{
    int idx = blockIdx.x * 256 + threadIdx.x;
    if (idx >= n4) return;
    float4 v = ((const float4*)in)[idx];
    short4 o;
    o.x = (short)f2b(v.x); o.y = (short)f2b(v.y);
    o.z = (short)f2b(v.z); o.w = (short)f2b(v.w);
    ((short4*)out)[idx] = o;
}

// ---------------------------------------------------------------------------
// h0[:, :256] = mx ; h0[:, 256:512] = 0
// ---------------------------------------------------------------------------
__global__ __launch_bounds__(256) void init_h0_kernel(
    const float* __restrict__ mx, float* __restrict__ h0, int total4)
{
    int idx = blockIdx.x * 256 + threadIdx.x;
    if (idx >= total4) return;
    int r  = idx >> 7;
    int c4 = idx & 127;
    float4 v;
    if (c4 < 64) v = ((const float4*)mx)[(size_t)r * 64 + c4];
    else         v = make_float4(0.f, 0.f, 0.f, 0.f);
    ((float4*)h0)[idx] = v;
}

// ---------------------------------------------------------------------------
// Scatter: one wave per edge; fuses me_x pass-through copy.
// ---------------------------------------------------------------------------
__global__ __launch_bounds__(256) void scatter_kernel(
    const float* __restrict__ me_x, const int* __restrict__ me_i,
    float* __restrict__ out_mex, float* __restrict__ h0, int E)
{
    int idx = blockIdx.x * 256 + threadIdx.x;
    int e  = idx >> 6;
    if (e >= E) return;
    int f4 = idx & 63;
    float4 v = ((const float4*)me_x)[idx];
    ((float4*)out_mex)[idx] = v;
    int col = me_i[E + e];
    float* dst = h0 + (size_t)col * 512 + 256 + (size_t)f4 * 4;
    unsafeAtomicAdd(dst + 0, v.x);
    unsafeAtomicAdd(dst + 1, v.y);
    unsafeAtomicAdd(dst + 2, v.z);
    unsafeAtomicAdd(dst + 3, v.w);
}

// ---------------------------------------------------------------------------
// bf16 MFMA GEMM: C[M,N] = act(A[M,K] @ W[N,K]^T + bias)
// A,W bf16 (K contiguous). 128x128 tile, BK=32, 4 waves (2x2, 64x64 each,
// 4x4 frags of 16x16x32). global_load_lds width-16 staging, linear LDS
// [128 rows][64B]. ACT: 1=SiLU. OUT_BF16: 1 -> bf16 C, else f32 C.
// ---------------------------------------------------------------------------
template<int ACT, int OUT_BF16>
__global__ __launch_bounds__(256) void gemm_bf16_kernel(
    const unsigned short* __restrict__ A, const unsigned short* __restrict__ W,
    const float* __restrict__ bias, void* __restrict__ C,
    int M, int N, int K)
{
    __shared__ uint4 lds_buf[1024];                  // 16 KB
    char* As = (char*)lds_buf;                       // 8 KB: [128][64B]
    char* Bs = (char*)lds_buf + 8192;                // 8 KB

    const int tid  = threadIdx.x;
    const int wid  = tid >> 6, lane = tid & 63;
    const int row0 = blockIdx.x * 128, col0 = blockIdx.y * 128;
    const int wr = (wid >> 1) * 64, wc = (wid & 1) * 64;

    f32x4 acc[4][4] = {};

    // staging geometry: issue i covers LDS bytes i*1024..+1024 = rows i*16..+15
    const int srow0  = wid * 16 + (lane >> 2);       // issue wid
    const int srow1  = (wid + 4) * 16 + (lane >> 2); // issue wid+4
    const int sck    = (lane & 3) * 16;              // byte offset in 64B row
    const int arow0  = min(row0 + srow0, M - 1);     // clamp M-tail
    const int arow1  = min(row0 + srow1, M - 1);
    const int wrow0  = col0 + srow0;                 // N multiple of 128
    const int wrow1  = col0 + srow1;

    for (int k0 = 0; k0 < K; k0 += 32) {
        __syncthreads();
        gload_lds16((const char*)(A + (size_t)arow0 * K + k0) + sck, As + wid * 1024);
        gload_lds16((const char*)(A + (size_t)arow1 * K + k0) + sck, As + (wid + 4) * 1024);
        gload_lds16((const char*)(W + (size_t)wrow0 * K + k0) + sck, Bs + wid * 1024);
        gload_lds16((const char*)(W + (size_t)wrow1 * K + k0) + sck, Bs + (wid + 4) * 1024);
        asm volatile("s_waitcnt vmcnt(0)" ::: "memory");
        __syncthreads();

        bf16x8 af[4], bf[4];
        const int kc = (lane >> 4) * 16;             // 16B chunk per lane-group
#pragma unroll
        for (int m = 0; m < 4; ++m)
            af[m] = *(const bf16x8*)(As + (wr + m * 16 + (lane & 15)) * 64 + kc);
#pragma unroll
        for (int n = 0; n < 4; ++n)
            bf[n] = *(const bf16x8*)(Bs + (wc + n * 16 + (lane & 15)) * 64 + kc);
#pragma unroll
        for (int m = 0; m < 4; ++m)
#pragma unroll
            for (int n = 0; n < 4; ++n)
                acc[m][n] = __builtin_amdgcn_mfma_f32_16x16x32_bf16(
                    af[m], bf[n], acc[m][n], 0, 0, 0);
    }

    // epilogue: C/D layout col=lane&15, row=(lane>>4)*4+reg (m89-verified)
    const int ccol  = wc + (lane & 15);
    const int crow0 = wr + (lane >> 4) * 4;
    float bval[4];
#pragma unroll
    for (int n = 0; n < 4; ++n) bval[n] = bias[col0 + ccol + n * 16];

#pragma unroll
    for (int m = 0; m < 4; ++m) {
#pragma unroll
        for (int r = 0; r < 4; ++r) {
            int row = row0 + crow0 + m * 16 + r;
            if (row >= M) continue;
#pragma unroll
            for (int n = 0; n < 4; ++n) {
                float x = acc[m][n][r] + bval[n];
                if (ACT) x = x / (1.f + __expf(-x));
                size_t off = (size_t)row * N + col0 + ccol + n * 16;
                if (OUT_BF16) ((unsigned short*)C)[off] = f2b(x);
                else          ((float*)C)[off] = x;
            }
        }
    }
}

// ---------------------------------------------------------------------------
// Global sum / sumsq of h3 (double accumulation)
// ---------------------------------------------------------------------------
__global__ __launch_bounds__(256) void reduce_kernel(
    const float* __restrict__ h, double* __restrict__ sums, int n4)
{
    double s = 0.0, s2 = 0.0;
    for (int idx = blockIdx.x * 256 + threadIdx.x; idx < n4;
         idx += gridDim.x * 256) {
        float4 v = ((const float4*)h)[idx];
        s  += (double)v.x + (double)v.y + (double)v.z + (double)v.w;
        s2 += (double)v.x * v.x + (double)v.y * v.y
            + (double)v.z * v.z + (double)v.w * v.w;
    }
#pragma unroll
    for (int off = 32; off > 0; off >>= 1) {
        s  += __shfl_down(s,  off, 64);
        s2 += __shfl_down(s2, off, 64);
    }
    __shared__ double lds[8];
    int wid = threadIdx.x >> 6, lane = threadIdx.x & 63;
    if (lane == 0) { lds[wid] = s; lds[wid + 4] = s2; }
    __syncthreads();
    if (threadIdx.x == 0) {
        unsafeAtomicAdd(&sums[0], lds[0] + lds[1] + lds[2] + lds[3]);
        unsafeAtomicAdd(&sums[1], lds[4] + lds[5] + lds[6] + lds[7]);
    }
}

__global__ __launch_bounds__(256) void finalize_kernel(
    const float* __restrict__ h3, const float* __restrict__ mx,
    const float* __restrict__ gamma, const float* __restrict__ beta,
    const double* __restrict__ sums, float* __restrict__ out_mx, int n4)
{
    int idx = blockIdx.x * 256 + threadIdx.x;
    if (idx >= n4) return;
    const double NT = (double)kMNUM * 256.0;
    double mu  = sums[0] / NT;
    double var = sums[1] / NT - mu * mu;
    float fmu = (float)mu;
    float rs  = (float)(1.0 / sqrt(var + 1e-5));

    float4 h = ((const float4*)h3)[idx];
    float4 m = ((const float4*)mx)[idx];
    float4 g = ((const float4*)gamma)[idx];
    float4 b = ((const float4*)beta)[idx];
    float4 o;
    o.x = m.x + (h.x - fmu) * rs * g.x + b.x;
    o.y = m.y + (h.y - fmu) * rs * g.y + b.y;
    o.z = m.z + (h.z - fmu) * rs * g.z + b.z;
    o.w = m.w + (h.w - fmu) * rs * g.w + b.w;
    ((float4*)out_mx)[idx] = o;
}

// ---------------------------------------------------------------------------
extern "C" void kernel_launch(void* const* d_in, const int* in_sizes, int n_in,
                              void* d_out, int out_size, void* d_ws, size_t ws_size,
                              hipStream_t stream)
{
    const float* gx     = (const float*)d_in[0];
    const float* mx     = (const float*)d_in[1];
    const int*   me_i   = (const int*)  d_in[2];
    const float* me_x   = (const float*)d_in[3];
    const int*   g2me_i = (const int*)  d_in[4];
    const float* g2me_x = (const float*)d_in[5];
    const int*   m2ge_i = (const int*)  d_in[6];
    const float* m2ge_x = (const float*)d_in[7];
    const float* W1 = (const float*)d_in[8];
    const float* b1 = (const float*)d_in[9];
    const float* W2 = (const float*)d_in[10];
    const float* b2 = (const float*)d_in[11];
    const float* W3 = (const float*)d_in[12];
    const float* b3 = (const float*)d_in[13];
    const float* gamma = (const float*)d_in[14];
    const float* beta  = (const float*)d_in[15];

    float* out = (float*)d_out;
    char*  wsb = (char*)d_ws;

    float*          h0   = (float*)(wsb + B_H0);
    unsigned short* h0b  = (unsigned short*)(wsb + B_H0B);
    unsigned short* h1b  = (unsigned short*)(wsb + B_H1B);
    unsigned short* h2b  = (unsigned short*)(wsb + B_H2B);
    float*          h3   = (float*)(wsb + B_H3);
    unsigned short* wb   = (unsigned short*)(wsb + B_WB);
    double*         sums = (double*)(wsb + B_SUM);

    // ---- pass-through copies (me_x fused into scatter) ----
    hipMemcpyAsync(out + O_GX,  gx,     N_GX  * 4, hipMemcpyDeviceToDevice, stream);
    hipMemcpyAsync(out + O_G2X, g2me_x, N_G2X * 4, hipMemcpyDeviceToDevice, stream);
    hipMemcpyAsync(out + O_M2X, m2ge_x, N_M2X * 4, hipMemcpyDeviceToDevice, stream);

    // ---- index tensors: int32 -> float32 VALUE conversion ----
    i2f_kernel<<<(int)(N_MEI / 4 + 255) / 256, 256, 0, stream>>>(me_i,   out + O_MEI, (int)(N_MEI / 4));
    i2f_kernel<<<(int)(N_G2I / 4 + 255) / 256, 256, 0, stream>>>(g2me_i, out + O_G2I, (int)(N_G2I / 4));
    i2f_kernel<<<(int)(N_M2I / 4 + 255) / 256, 256, 0, stream>>>(m2ge_i, out + O_M2I, (int)(N_M2I / 4));

    hipMemsetAsync(sums, 0, 2 * sizeof(double), stream);

    // ---- weights -> bf16 (tiny) ----
    f2b_kernel<<<(512 * 512 / 4 + 255) / 256, 256, 0, stream>>>(W1, wb + WB_W1, 512 * 512 / 4);
    f2b_kernel<<<(256 * 512 / 4 + 255) / 256, 256, 0, stream>>>(W2, wb + WB_W2, 256 * 512 / 4);
    f2b_kernel<<<(256 * 256 / 4 + 255) / 256, 256, 0, stream>>>(W3, wb + WB_W3, 256 * 256 / 4);

    // ---- h0 = [mx | 0]; scatter edges; h0 -> bf16 ----
    {
        int total4 = kMNUM * 128;
        init_h0_kernel<<<(total4 + 255) / 256, 256, 0, stream>>>(mx, h0, total4);
    }
    {
        int total = kEDGES * 64;
        scatter_kernel<<<(total + 255) / 256, 256, 0, stream>>>(
            me_x, me_i, out + O_MEX, h0, kEDGES);
    }
    {
        int n4 = kMNUM * 512 / 4;
        f2b_kernel<<<(n4 + 255) / 256, 256, 0, stream>>>(h0, h0b, n4);
    }

    // ---- MLP (bf16 MFMA) ----
    {
        dim3 g1((kMNUM + 127) / 128, 4);
        gemm_bf16_kernel<1, 1><<<g1, 256, 0, stream>>>(h0b, wb + WB_W1, b1, h1b, kMNUM, 512, 512);
        dim3 g2((kMNUM + 127) / 128, 2);
        gemm_bf16_kernel<1, 1><<<g2, 256, 0, stream>>>(h1b, wb + WB_W2, b2, h2b, kMNUM, 256, 512);
        dim3 g3((kMNUM + 127) / 128, 2);
        gemm_bf16_kernel<0, 0><<<g3, 256, 0, stream>>>(h2b, wb + WB_W3, b3, h3, kMNUM, 256, 256);
    }

    // ---- global LayerNorm stats + finalize ----
    {
        int n4 = kMNUM * 256 / 4;
        reduce_kernel<<<2048, 256, 0, stream>>>(h3, sums, n4);
        finalize_kernel<<<(n4 + 255) / 256, 256, 0, stream>>>(
            h3, mx, gamma, beta, sums, out + O_MX, n4);
    }
}